// Round 5
// baseline (437.774 us; speedup 1.0000x reference)
//
#include <hip/hip_runtime.h>

// ReaxFF bond energy + segment_sum. N_BONDS=16777216, N_ATOMS=1048576, N_TYPES=16.
//
// R6: 512 buckets, CB=8192, NR=2 -> 125 us/round partition.
// R7: occupancy 36->64% -> no gain. Wave count is NOT the limiter.
// R8: PADQ/swizzle/prefetch -> no gain. Write-"amplification" ~1.9x invariant.
// R10: 64 coarse buckets -> 105 us/round partition (7.7 cyc/bond/CU).
//      Audit: VALU ~0.2, LDS ~0.7, HBM@peak ~0.8 cyc/bond -> ~80% unexplained
//      stall; realized read BW 2.28 TB/s vs 6.3 plain-load copy ceiling.
//      VALUBusy(84%) inconsistent with instruction count -> formula artifact.
// R11 (this): (a) fuse count into partition: pass0 holds atom_i in REGISTERS
//      (av[8]), LDS hist, wave-shfl scan, per-bucket slab reservation via ONE
//      global atomicAdd per bucket (overflow -> rare direct-atomic fallback).
//      Kills count/scan/base kernels + 67 MB HBM re-read. (b) drop
//      nontemporal on partition streams (unconfounded A/B vs m13's 6.3 TB/s
//      plain-load ceiling). (c) NR=1 fits in ~88 MB; NR=2 tier (53.5 MB,
//      proven fit) inherits everything.

typedef float    f32x4 __attribute__((ext_vector_type(4)));
typedef int      i32x4 __attribute__((ext_vector_type(4)));
typedef unsigned u32x4 __attribute__((ext_vector_type(4)));
typedef unsigned u32;

#define NBUK   64       // coarse buckets; bucket covers 16384 atoms
#define RANGEK 16384
#define SHIFTK 14
#define CB     8192     // bonds per superblock
#define TB     256
#define PADQ   8u       // run padding quantum (8 elems = 32 B sector)
#define SPLITS 4        // accum blocks per bucket

__device__ __forceinline__ u32 f32_to_bf16_bits(float f) {
    u32 u = __float_as_uint(f);
    return ((u + 0x7FFFu + ((u >> 16) & 1u)) >> 16) & 0xFFFFu;
}

// ---- Pass B: count (in-register) + LDS counting sort + slab run writes ----
__global__ __launch_bounds__(TB, 4) void partition_kernel(
        const i32x4* __restrict__ bt, const i32x4* __restrict__ ai,
        const f32x4* __restrict__ bs_, const f32x4* __restrict__ bp_,
        const f32x4* __restrict__ bpp_, const float* __restrict__ bond_params,
        u32* __restrict__ gcur, u32* __restrict__ arena,
        float* __restrict__ out, u32 slab, int round_start) {
    __shared__ u32   sorted[CB];        // 32 KB
    __shared__ u32   hist[4][NBUK];     // 1 KB
    __shared__ u32   start_[NBUK], cur[NBUK], graw_[NBUK], ovf_[NBUK];
    __shared__ float4 sp_a[16];         // de_s, de_p, de_pp, p_be1
    __shared__ float  sp_b[16];         // p_be2

    int tid = threadIdx.x, sb = blockIdx.x;
    ((u32*)hist)[tid] = 0u;             // TB == 4*NBUK exactly
    if (tid < 16) {
        const float* p = bond_params + tid * 5;
        sp_a[tid] = make_float4(p[0], p[1], p[2], p[3]);
        sp_b[tid] = p[4];
    }
    __syncthreads();

    // pass0: load atom_i into registers (kept for pass1), build histogram
    long base4 = ((long)round_start + (long)sb * CB) >> 2;
    int w = tid >> 6;
    i32x4 av[CB / (TB * 4)];
#pragma unroll
    for (int it = 0; it < CB / (TB * 4); ++it) {
        av[it] = ai[base4 + it * TB + tid];
        atomicAdd(&hist[w][(u32)av[it].x >> SHIFTK], 1u);
        atomicAdd(&hist[w][(u32)av[it].y >> SHIFTK], 1u);
        atomicAdd(&hist[w][(u32)av[it].z >> SHIFTK], 1u);
        atomicAdd(&hist[w][(u32)av[it].w >> SHIFTK], 1u);
    }
    __syncthreads();

    // cnt -> local scan (one wave, shfl) -> global slab reservation
    if (tid < 64) {
        u32 c = hist[0][tid] + hist[1][tid] + hist[2][tid] + hist[3][tid];
        u32 s = c;
#pragma unroll
        for (int off = 1; off < 64; off <<= 1) {
            u32 n = __shfl_up(s, off);
            if (tid >= off) s += n;
        }
        start_[tid] = s - c;
        cur[tid]    = s - c;
        u32 plen = (c + PADQ - 1u) & ~(PADQ - 1u);
        u32 g = atomicAdd(&gcur[tid], plen);   // device-scope by default
        graw_[tid] = g;
        ovf_[tid]  = (g + plen > slab) ? 1u : 0u;
    }
    __syncthreads();

    // pass1: compute e, scatter into LDS by bucket (plain cached loads)
#pragma unroll
    for (int it = 0; it < CB / (TB * 4); ++it) {
        long idx = base4 + it * TB + tid;
        i32x4 t  = bt[idx];
        f32x4 s  = bs_[idx];
        f32x4 p  = bp_[idx];
        f32x4 pp = bpp_[idx];
        i32x4 a  = av[it];
#pragma unroll
        for (int k = 0; k < 4; ++k) {
            u32 ak = (u32)a[k];
            float4 pa = sp_a[t[k]];      // one ds_read_b128
            float  pb = sp_b[t[k]];      // one ds_read_b32
            float pw = __powf(s[k], pb); // s in (0.05,1) -> safe
            float e  = -pa.x * s[k] * __expf(pa.w * (1.0f - pw))
                       - pa.y * p[k] - pa.z * pp[k];
            u32 b = ak >> SHIFTK;
            u32 pos = atomicAdd(&cur[b], 1u);
            sorted[pos] = ((ak & (RANGEK - 1u)) << 16) | f32_to_bf16_bits(e);
        }
    }
    __syncthreads();

    // copy-out: one wave per bucket, coalesced padded runs into bucket slab
    int lane = tid & 63;
    for (int b = w; b < NBUK; b += 4) {
        u32 ls = start_[b], len = cur[b] - ls;
        u32 plen = (len + PADQ - 1u) & ~(PADQ - 1u);
        u32 g = graw_[b];
        if (!ovf_[b]) {
            size_t base = (size_t)b * slab + g;
            for (u32 j = lane; j < plen; j += 64u)
                arena[base + j] = (j < len) ? sorted[ls + j] : 0u;
        } else {
            // zero-fill the clipped reservation so accum sees pads only
            u32 z0 = g < slab ? g : slab;
            u32 z1 = (g + plen) < slab ? (g + plen) : slab;
            for (u32 j = z0 + lane; j < z1; j += 64u)
                arena[(size_t)b * slab + j] = 0u;
            // rare: add bonds directly into pre-zeroed out
            for (u32 j = lane; j < len; j += 64u) {
                u32 e = sorted[ls + j];
                unsafeAtomicAdd(&out[((u32)b << SHIFTK) + (e >> 16)],
                                __uint_as_float((e & 0xFFFFu) << 16));
            }
        }
    }
}

// ---- Pass C: per-bucket-split LDS f32 accumulation (64 KB acc) ----
__global__ __launch_bounds__(1024) void accum_kernel(
        const u32* __restrict__ arena, const u32* __restrict__ gcur,
        float* __restrict__ partials, u32 slab) {
    __shared__ float acc[RANGEK];       // 64 KB
    int tid = threadIdx.x;
    int b = blockIdx.x >> 2, sp = blockIdx.x & 3;
    f32x4* a4 = (f32x4*)acc;
#pragma unroll
    for (int i = 0; i < RANGEK / 4 / 1024; ++i)
        a4[i * 1024 + tid] = (f32x4)(0.f);
    __syncthreads();
    u32 n = gcur[b];
    if (n > slab) n = slab;             // overflow tail handled by partition
    u32 nv = n >> 2;                    // u32x4 groups (n multiple of 8)
    const u32x4* src = (const u32x4*)(arena + (size_t)b * slab);
    for (u32 j = (u32)sp * 1024u + tid; j < nv; j += 4096u) {
        u32x4 e = __builtin_nontemporal_load(&src[j]);
        // pad entries are 0 -> add 0.0f to acc[0]: harmless, branch-free
        atomicAdd(&acc[e.x >> 16], __uint_as_float((e.x & 0xFFFFu) << 16));
        atomicAdd(&acc[e.y >> 16], __uint_as_float((e.y & 0xFFFFu) << 16));
        atomicAdd(&acc[e.z >> 16], __uint_as_float((e.z & 0xFFFFu) << 16));
        atomicAdd(&acc[e.w >> 16], __uint_as_float((e.w & 0xFFFFu) << 16));
    }
    __syncthreads();
    f32x4* pr = (f32x4*)(partials + ((size_t)sp * NBUK + b) * RANGEK);
#pragma unroll
    for (int i = 0; i < RANGEK / 4 / 1024; ++i)
        pr[i * 1024 + tid] = a4[i * 1024 + tid];
}

// ---- Merge: out += sum of SPLITS partials (out pre-zeroed; keeps overflow) --
__global__ __launch_bounds__(TB) void merge_kernel(
        const float* __restrict__ partials, float* __restrict__ out,
        int n_atoms) {
    int i = blockIdx.x * TB + threadIdx.x;
    const f32x4* p0 = (const f32x4*)partials;
    const f32x4* p1 = (const f32x4*)(partials + (size_t)n_atoms);
    const f32x4* p2 = (const f32x4*)(partials + 2 * (size_t)n_atoms);
    const f32x4* p3 = (const f32x4*)(partials + 3 * (size_t)n_atoms);
    f32x4* o4 = (f32x4*)out;
    o4[i] += p0[i] + p1[i] + p2[i] + p3[i];
}

// ---- zero + device-atomic fallback ----
__global__ __launch_bounds__(TB) void zero_kernel(f32x4* __restrict__ p, int n4) {
    int i = blockIdx.x * blockDim.x + threadIdx.x;
    if (i < n4) p[i] = (f32x4)(0.f);
}

__global__ __launch_bounds__(TB) void atomic_fallback_kernel(
        const i32x4* __restrict__ bt, const i32x4* __restrict__ ai,
        const f32x4* __restrict__ bs_, const f32x4* __restrict__ bp_,
        const f32x4* __restrict__ bpp_, const float* __restrict__ bond_params,
        float* __restrict__ out, int n4) {
    __shared__ float sp[80];
    if (threadIdx.x < 80) sp[threadIdx.x] = bond_params[threadIdx.x];
    __syncthreads();
    int i = blockIdx.x * blockDim.x + threadIdx.x;
    if (i >= n4) return;
    i32x4 t  = bt[i]; i32x4 a = ai[i];
    f32x4 s  = bs_[i]; f32x4 p = bp_[i]; f32x4 pp = bpp_[i];
#pragma unroll
    for (int k = 0; k < 4; ++k) {
        const float* pr = sp + t[k] * 5;
        float pw = __powf(s[k], pr[4]);
        float e  = -pr[0] * s[k] * __expf(pr[3] * (1.0f - pw))
                   - pr[1] * p[k] - pr[2] * pp[k];
        unsafeAtomicAdd(&out[a[k]], e);
    }
}

extern "C" void kernel_launch(void* const* d_in, const int* in_sizes, int n_in,
                              void* d_out, int out_size, void* d_ws, size_t ws_size,
                              hipStream_t stream) {
    const int*   bond_type   = (const int*)  d_in[0];
    const int*   atom_i      = (const int*)  d_in[1];
    const float* bo_sigma    = (const float*)d_in[2];
    const float* bo_pi       = (const float*)d_in[3];
    const float* bo_pipi     = (const float*)d_in[4];
    const float* bond_params = (const float*)d_in[5];
    float*       e_atom      = (float*)d_out;

    const int n_bonds = in_sizes[0];
    const int n_atoms = out_size;

    // Fewest rounds whose slab workspace fits.
    // slab = per-bucket mean + pad budget (nsb*4 covers avg 3.5/run) + 16sigma.
    int cfg_nr = 0; u32 cfg_slab = 0;
    if (n_atoms == (NBUK << SHIFTK)) {
        const int cands[5] = {1, 2, 4, 8, 16};
        for (int ci = 0; ci < 5 && !cfg_nr; ++ci) {
            int r = cands[ci];
            if (n_bonds % (r * CB)) continue;
            long cpr = (long)n_bonds / r, nsb = cpr / CB;
            if (nsb < 256 || nsb > 8192) continue;
            u32 sl = (u32)((cpr / NBUK + nsb * 4 + 8192 + 7) & ~7L);
            size_t need = (size_t)NBUK * sl * 4
                        + 1024                            // gcur (+pad)
                        + (size_t)SPLITS * n_atoms * 4;   // partials
            if (need <= ws_size) { cfg_nr = r; cfg_slab = sl; }
        }
    }

    if (cfg_nr) {
        const int NR = cfg_nr, cpr = n_bonds / NR, nsb = cpr / CB;
        u32*   arena    = (u32*)d_ws;
        u32*   gcur     = arena + (size_t)NBUK * cfg_slab;
        float* partials = (float*)(gcur + 256);
        int zn4 = n_atoms / 4;
        zero_kernel<<<(zn4 + TB - 1) / TB, TB, 0, stream>>>((f32x4*)e_atom, zn4);
        for (int r = 0; r < NR; ++r) {
            int rs = r * cpr;
            hipMemsetAsync(gcur, 0, NBUK * sizeof(u32), stream);
            partition_kernel<<<nsb, TB, 0, stream>>>(
                (const i32x4*)bond_type, (const i32x4*)atom_i,
                (const f32x4*)bo_sigma, (const f32x4*)bo_pi, (const f32x4*)bo_pipi,
                bond_params, gcur, arena, e_atom, cfg_slab, rs);
            accum_kernel<<<NBUK * SPLITS, 1024, 0, stream>>>(
                arena, gcur, partials, cfg_slab);
            merge_kernel<<<n_atoms / 4 / TB, TB, 0, stream>>>(
                partials, e_atom, n_atoms);
        }
    } else {
        int zn4 = n_atoms / 4;
        zero_kernel<<<(zn4 + TB - 1) / TB, TB, 0, stream>>>((f32x4*)e_atom, zn4);
        int n4 = n_bonds / 4;
        atomic_fallback_kernel<<<(n4 + TB - 1) / TB, TB, 0, stream>>>(
            (const i32x4*)bond_type, (const i32x4*)atom_i,
            (const f32x4*)bo_sigma, (const f32x4*)bo_pi, (const f32x4*)bo_pipi,
            bond_params, e_atom, n4);
    }
}

// Round 6
// 429.011 us; speedup vs baseline: 1.0204x; 1.0204x over previous
//
#include <hip/hip_runtime.h>

// ReaxFF bond energy + segment_sum. N_BONDS=16777216, N_ATOMS=1048576, N_TYPES=16.
//
// R6: 512 buckets, CB=8192, NR=2 -> 125 us/round partition.
// R7: occupancy 36->64% -> no gain. Wave count is NOT the limiter.
// R10: 64 coarse buckets, NT loads -> 105 us/round partition @ 2.28 TB/s.
// R11: fused count into partition (av[] registers, slab reservation) but
//      switched to plain loads -> 158 us @ 1.51 TB/s. 158/105 == 2.28/1.51:
//      regression is ENTIRELY the NT removal; fusion is byte-neutral.
//      RULE (A/B-confirmed): __builtin_nontemporal_load = +50% realized BW
//      on multi-stream reads here (no-allocate keeps L2 for the write stream).
// R12 (this): R11 structure + NT loads restored everywhere in partition.
//      SPLITS made runtime; NR=1 tiers (trimmed slab, SPLITS 4/2/1) tried
//      before the proven NR=2 tier. Overflow path is correct-by-construction,
//      so aggressive slab sizing is safe.

typedef float    f32x4 __attribute__((ext_vector_type(4)));
typedef int      i32x4 __attribute__((ext_vector_type(4)));
typedef unsigned u32x4 __attribute__((ext_vector_type(4)));
typedef unsigned u32;

#define NBUK   64       // coarse buckets; bucket covers 16384 atoms
#define RANGEK 16384
#define SHIFTK 14
#define CB     8192     // bonds per superblock
#define TB     256
#define PADQ   8u       // run padding quantum (8 elems = 32 B sector)

__device__ __forceinline__ u32 f32_to_bf16_bits(float f) {
    u32 u = __float_as_uint(f);
    return ((u + 0x7FFFu + ((u >> 16) & 1u)) >> 16) & 0xFFFFu;
}

// ---- Pass B: count (in-register) + LDS counting sort + slab run writes ----
__global__ __launch_bounds__(TB, 4) void partition_kernel(
        const i32x4* __restrict__ bt, const i32x4* __restrict__ ai,
        const f32x4* __restrict__ bs_, const f32x4* __restrict__ bp_,
        const f32x4* __restrict__ bpp_, const float* __restrict__ bond_params,
        u32* __restrict__ gcur, u32* __restrict__ arena,
        float* __restrict__ out, u32 slab, int round_start) {
    __shared__ u32   sorted[CB];        // 32 KB
    __shared__ u32   hist[4][NBUK];     // 1 KB
    __shared__ u32   start_[NBUK], cur[NBUK], graw_[NBUK], ovf_[NBUK];
    __shared__ float4 sp_a[16];         // de_s, de_p, de_pp, p_be1
    __shared__ float  sp_b[16];         // p_be2

    int tid = threadIdx.x, sb = blockIdx.x;
    ((u32*)hist)[tid] = 0u;             // TB == 4*NBUK exactly
    if (tid < 16) {
        const float* p = bond_params + tid * 5;
        sp_a[tid] = make_float4(p[0], p[1], p[2], p[3]);
        sp_b[tid] = p[4];
    }
    __syncthreads();

    // pass0: load atom_i into registers (kept for pass1), build histogram
    long base4 = ((long)round_start + (long)sb * CB) >> 2;
    int w = tid >> 6;
    i32x4 av[CB / (TB * 4)];
#pragma unroll
    for (int it = 0; it < CB / (TB * 4); ++it) {
        av[it] = __builtin_nontemporal_load(&ai[base4 + it * TB + tid]);
        atomicAdd(&hist[w][(u32)av[it].x >> SHIFTK], 1u);
        atomicAdd(&hist[w][(u32)av[it].y >> SHIFTK], 1u);
        atomicAdd(&hist[w][(u32)av[it].z >> SHIFTK], 1u);
        atomicAdd(&hist[w][(u32)av[it].w >> SHIFTK], 1u);
    }
    __syncthreads();

    // cnt -> local scan (one wave, shfl) -> global slab reservation
    if (tid < 64) {
        u32 c = hist[0][tid] + hist[1][tid] + hist[2][tid] + hist[3][tid];
        u32 s = c;
#pragma unroll
        for (int off = 1; off < 64; off <<= 1) {
            u32 n = __shfl_up(s, off);
            if (tid >= off) s += n;
        }
        start_[tid] = s - c;
        cur[tid]    = s - c;
        u32 plen = (c + PADQ - 1u) & ~(PADQ - 1u);
        u32 g = atomicAdd(&gcur[tid], plen);   // device-scope by default
        graw_[tid] = g;
        ovf_[tid]  = (g + plen > slab) ? 1u : 0u;
    }
    __syncthreads();

    // pass1: compute e, scatter into LDS by bucket (NT streaming loads)
#pragma unroll
    for (int it = 0; it < CB / (TB * 4); ++it) {
        long idx = base4 + it * TB + tid;
        i32x4 t  = __builtin_nontemporal_load(&bt[idx]);
        f32x4 s  = __builtin_nontemporal_load(&bs_[idx]);
        f32x4 p  = __builtin_nontemporal_load(&bp_[idx]);
        f32x4 pp = __builtin_nontemporal_load(&bpp_[idx]);
        i32x4 a  = av[it];
#pragma unroll
        for (int k = 0; k < 4; ++k) {
            u32 ak = (u32)a[k];
            float4 pa = sp_a[t[k]];      // one ds_read_b128
            float  pb = sp_b[t[k]];      // one ds_read_b32
            float pw = __powf(s[k], pb); // s in (0.05,1) -> safe
            float e  = -pa.x * s[k] * __expf(pa.w * (1.0f - pw))
                       - pa.y * p[k] - pa.z * pp[k];
            u32 b = ak >> SHIFTK;
            u32 pos = atomicAdd(&cur[b], 1u);
            sorted[pos] = ((ak & (RANGEK - 1u)) << 16) | f32_to_bf16_bits(e);
        }
    }
    __syncthreads();

    // copy-out: one wave per bucket, coalesced padded runs into bucket slab
    int lane = tid & 63;
    for (int b = w; b < NBUK; b += 4) {
        u32 ls = start_[b], len = cur[b] - ls;
        u32 plen = (len + PADQ - 1u) & ~(PADQ - 1u);
        u32 g = graw_[b];
        if (!ovf_[b]) {
            size_t base = (size_t)b * slab + g;
            for (u32 j = lane; j < plen; j += 64u)
                arena[base + j] = (j < len) ? sorted[ls + j] : 0u;
        } else {
            // zero-fill the clipped reservation so accum sees pads only
            u32 z0 = g < slab ? g : slab;
            u32 z1 = (g + plen) < slab ? (g + plen) : slab;
            for (u32 j = z0 + lane; j < z1; j += 64u)
                arena[(size_t)b * slab + j] = 0u;
            // rare: add bonds directly into pre-zeroed out
            for (u32 j = lane; j < len; j += 64u) {
                u32 e = sorted[ls + j];
                unsafeAtomicAdd(&out[((u32)b << SHIFTK) + (e >> 16)],
                                __uint_as_float((e & 0xFFFFu) << 16));
            }
        }
    }
}

// ---- Pass C: per-bucket-split LDS f32 accumulation (64 KB acc) ----
__global__ __launch_bounds__(1024) void accum_kernel(
        const u32* __restrict__ arena, const u32* __restrict__ gcur,
        float* __restrict__ partials, u32 slab, int splits) {
    __shared__ float acc[RANGEK];       // 64 KB
    int tid = threadIdx.x;
    int b = blockIdx.x / splits, sp = blockIdx.x % splits;
    f32x4* a4 = (f32x4*)acc;
#pragma unroll
    for (int i = 0; i < RANGEK / 4 / 1024; ++i)
        a4[i * 1024 + tid] = (f32x4)(0.f);
    __syncthreads();
    u32 n = gcur[b];
    if (n > slab) n = slab;             // overflow tail handled by partition
    u32 nv = n >> 2;                    // u32x4 groups (n multiple of 8)
    u32 stride = (u32)splits * 1024u;
    const u32x4* src = (const u32x4*)(arena + (size_t)b * slab);
    for (u32 j = (u32)sp * 1024u + tid; j < nv; j += stride) {
        u32x4 e = __builtin_nontemporal_load(&src[j]);
        // pad entries are 0 -> add 0.0f to acc[0]: harmless, branch-free
        atomicAdd(&acc[e.x >> 16], __uint_as_float((e.x & 0xFFFFu) << 16));
        atomicAdd(&acc[e.y >> 16], __uint_as_float((e.y & 0xFFFFu) << 16));
        atomicAdd(&acc[e.z >> 16], __uint_as_float((e.z & 0xFFFFu) << 16));
        atomicAdd(&acc[e.w >> 16], __uint_as_float((e.w & 0xFFFFu) << 16));
    }
    __syncthreads();
    f32x4* pr = (f32x4*)(partials + ((size_t)sp * NBUK + b) * RANGEK);
#pragma unroll
    for (int i = 0; i < RANGEK / 4 / 1024; ++i)
        pr[i * 1024 + tid] = a4[i * 1024 + tid];
}

// ---- Merge: out += sum of split partials (out pre-zeroed; keeps overflow) --
__global__ __launch_bounds__(TB) void merge_kernel(
        const float* __restrict__ partials, float* __restrict__ out,
        int n_atoms, int splits) {
    int i = blockIdx.x * TB + threadIdx.x;
    f32x4 v = ((const f32x4*)partials)[i];
    for (int s = 1; s < splits; ++s)
        v += ((const f32x4*)(partials + (size_t)s * n_atoms))[i];
    ((f32x4*)out)[i] += v;
}

// ---- zero + device-atomic fallback ----
__global__ __launch_bounds__(TB) void zero_kernel(f32x4* __restrict__ p, int n4) {
    int i = blockIdx.x * blockDim.x + threadIdx.x;
    if (i < n4) p[i] = (f32x4)(0.f);
}

__global__ __launch_bounds__(TB) void atomic_fallback_kernel(
        const i32x4* __restrict__ bt, const i32x4* __restrict__ ai,
        const f32x4* __restrict__ bs_, const f32x4* __restrict__ bp_,
        const f32x4* __restrict__ bpp_, const float* __restrict__ bond_params,
        float* __restrict__ out, int n4) {
    __shared__ float sp[80];
    if (threadIdx.x < 80) sp[threadIdx.x] = bond_params[threadIdx.x];
    __syncthreads();
    int i = blockIdx.x * blockDim.x + threadIdx.x;
    if (i >= n4) return;
    i32x4 t  = bt[i]; i32x4 a = ai[i];
    f32x4 s  = bs_[i]; f32x4 p = bp_[i]; f32x4 pp = bpp_[i];
#pragma unroll
    for (int k = 0; k < 4; ++k) {
        const float* pr = sp + t[k] * 5;
        float pw = __powf(s[k], pr[4]);
        float e  = -pr[0] * s[k] * __expf(pr[3] * (1.0f - pw))
                   - pr[1] * p[k] - pr[2] * pp[k];
        unsafeAtomicAdd(&out[a[k]], e);
    }
}

extern "C" void kernel_launch(void* const* d_in, const int* in_sizes, int n_in,
                              void* d_out, int out_size, void* d_ws, size_t ws_size,
                              hipStream_t stream) {
    const int*   bond_type   = (const int*)  d_in[0];
    const int*   atom_i      = (const int*)  d_in[1];
    const float* bo_sigma    = (const float*)d_in[2];
    const float* bo_pi       = (const float*)d_in[3];
    const float* bo_pipi     = (const float*)d_in[4];
    const float* bond_params = (const float*)d_in[5];
    float*       e_atom      = (float*)d_out;

    const int n_bonds = in_sizes[0];
    const int n_atoms = out_size;

    // Tier list: fewest rounds first (saves launch/merge overhead), then
    // fewer splits (smaller partials). Overflow path is correct, so slab
    // sizing is aggressive: mean + pad budget (nsb*4 ~ avg 3.5/run) + 4sigma.
    int cfg_nr = 0, cfg_sp = 0; u32 cfg_slab = 0;
    if (n_atoms == (NBUK << SHIFTK)) {
        const int prefs[8][2] = {   // {NR, SPLITS}
            {1, 4}, {1, 2}, {1, 1}, {2, 4}, {2, 2}, {4, 4}, {8, 4}, {16, 4}};
        for (int ci = 0; ci < 8 && !cfg_nr; ++ci) {
            int r = prefs[ci][0], spl = prefs[ci][1];
            if (n_bonds % (r * CB)) continue;
            long cpr = (long)n_bonds / r, nsb = cpr / CB;
            if (nsb < 256 || nsb > 8192) continue;
            u32 sl = (u32)((cpr / NBUK + nsb * 4 + 2048 + 7) & ~7L);
            size_t need = (size_t)NBUK * sl * 4
                        + 1024                          // gcur (+pad)
                        + (size_t)spl * n_atoms * 4;    // partials
            if (need <= ws_size) { cfg_nr = r; cfg_sp = spl; cfg_slab = sl; }
        }
    }

    if (cfg_nr) {
        const int NR = cfg_nr, cpr = n_bonds / NR, nsb = cpr / CB;
        u32*   arena    = (u32*)d_ws;
        u32*   gcur     = arena + (size_t)NBUK * cfg_slab;
        float* partials = (float*)(gcur + 256);
        int zn4 = n_atoms / 4;
        zero_kernel<<<(zn4 + TB - 1) / TB, TB, 0, stream>>>((f32x4*)e_atom, zn4);
        for (int r = 0; r < NR; ++r) {
            int rs = r * cpr;
            hipMemsetAsync(gcur, 0, NBUK * sizeof(u32), stream);
            partition_kernel<<<nsb, TB, 0, stream>>>(
                (const i32x4*)bond_type, (const i32x4*)atom_i,
                (const f32x4*)bo_sigma, (const f32x4*)bo_pi, (const f32x4*)bo_pipi,
                bond_params, gcur, arena, e_atom, cfg_slab, rs);
            accum_kernel<<<NBUK * cfg_sp, 1024, 0, stream>>>(
                arena, gcur, partials, cfg_slab, cfg_sp);
            merge_kernel<<<n_atoms / 4 / TB, TB, 0, stream>>>(
                partials, e_atom, n_atoms, cfg_sp);
        }
    } else {
        int zn4 = n_atoms / 4;
        zero_kernel<<<(zn4 + TB - 1) / TB, TB, 0, stream>>>((f32x4*)e_atom, zn4);
        int n4 = n_bonds / 4;
        atomic_fallback_kernel<<<(n4 + TB - 1) / TB, TB, 0, stream>>>(
            (const i32x4*)bond_type, (const i32x4*)atom_i,
            (const f32x4*)bo_sigma, (const f32x4*)bo_pi, (const f32x4*)bo_pipi,
            bond_params, e_atom, n4);
    }
}